// Round 9
// baseline (508.552 us; speedup 1.0000x reference)
//
#include <hip/hip_runtime.h>
#include <stdint.h>

#define BB 16
#define BG 4           // batches per group (temporal blocking for L3 ws residency)
#define NG (BB / BG)   // number of groups
#define LSEQ 8192
#define DD 512
#define PER 64
#define NBLK 128
#define QSCALE 0.45f

typedef __attribute__((ext_vector_type(8))) short short8;
typedef __attribute__((ext_vector_type(4))) float f32x4;
typedef __attribute__((ext_vector_type(2))) unsigned int uint2v;
typedef unsigned short ushort_t;

__device__ __forceinline__ ushort_t f2bf(float f) {
    union { float f; uint32_t u; } c; c.f = f;
    uint32_t u = c.u + 0x7FFFu + ((c.u >> 16) & 1u);
    return (ushort_t)(u >> 16);
}
__device__ __forceinline__ float bf2f(ushort_t h) {
    union { float f; uint32_t u; } c; c.u = ((uint32_t)h) << 16;
    return c.f;
}
__device__ __forceinline__ uint32_t pk2(float a, float b) {
    return (uint32_t)f2bf(a) | ((uint32_t)f2bf(b) << 16);
}

// ---- K_tr: merged q/k/v transposes for ONE GROUP of BG batches -------------
// z = role*BG + b_local; role 0: q->qT (scaled), 1: k->kT, 2: v->vTT.
// Pointers are pre-offset to the group's first batch; ws holds BG batches.
__global__ __launch_bounds__(256) void ktr(const float* __restrict__ q,
                                           const float* __restrict__ k,
                                           const float* __restrict__ v,
                                           ushort_t* __restrict__ qT,
                                           ushort_t* __restrict__ kT,
                                           ushort_t* __restrict__ vTT) {
    const int t = threadIdx.x;
    const int zz = blockIdx.z;
    const int role = zz >> 2;       // BG == 4
    const int b = zz & (BG - 1);
    if (role < 2) {
        const float scale = role ? 1.0f : QSCALE;
        const float* sp = (role ? k : q) + (size_t)b * LSEQ * DD;
        ushort_t* dp = (role ? kT : qT) + (size_t)b * DD * LSEQ;
        const int l0 = blockIdx.x * 64 + 4 * (t & 15);
        const int d0 = blockIdx.y * 64 + 4 * (t >> 4);
        f32x4 vv[4];
#pragma unroll
        for (int j = 0; j < 4; ++j)
            vv[j] = __builtin_nontemporal_load(
                (const f32x4*)(sp + (size_t)(l0 + j) * DD + d0));
#pragma unroll
        for (int dj = 0; dj < 4; ++dj) {
            uint2v w;
            w[0] = pk2(vv[0][dj] * scale, vv[1][dj] * scale);
            w[1] = pk2(vv[2][dj] * scale, vv[3][dj] * scale);
            *(uint2v*)(dp + (size_t)(d0 + dj) * LSEQ + l0) = w;  // cached: katt reads (L3-resident)
        }
    } else {
        // v: vtt[((b*D+d)*PER+p)*NBLK+m] = v[b, m*64+p, d]
        const int p = blockIdx.x & 63;
        const int mh = blockIdx.x >> 6;  // 0..1
        const int m0 = mh * 64 + 4 * (t & 15);
        const int d0 = blockIdx.y * 64 + 4 * (t >> 4);
        const float* vp = v + (size_t)b * LSEQ * DD;
        f32x4 x[4];
#pragma unroll
        for (int mj = 0; mj < 4; ++mj)
            x[mj] = __builtin_nontemporal_load(
                (const f32x4*)(vp + (size_t)((m0 + mj) * PER + p) * DD + d0));
#pragma unroll
        for (int dj = 0; dj < 4; ++dj) {
            uint2v w;
            w[0] = pk2(x[0][dj], x[1][dj]);
            w[1] = pk2(x[2][dj], x[3][dj]);
            *(uint2v*)(vTT + (size_t)((size_t)(b * DD + d0 + dj) * PER + p) * NBLK + m0) = w;
        }
    }
}

// ---------------- K_att: per-(b,d) attention with MFMA (group-local) --------
// LDS (48 KB, 3 blocks/CU):
//   Qs [128][64] @0, Ks [128][64] @8192 — dead after QK phase
//   Ps [128][128] OVERLAYS Qs+Ks (barrier in between); Vs [64][128] @16384
// XOR swizzle: granule' = granule ^ (row & 7)
__global__ __launch_bounds__(256, 3) void katt(const ushort_t* __restrict__ qT,
                                               const ushort_t* __restrict__ kT,
                                               const ushort_t* __restrict__ vTT,
                                               float* __restrict__ attn,
                                               ushort_t* __restrict__ outT) {
    __shared__ __align__(16) ushort_t sm[24576];
    ushort_t* Qs = sm;
    ushort_t* Ks = sm + 8192;
    ushort_t* Ps = sm;          // overlays Qs+Ks after QK phase
    ushort_t* Vs = sm + 16384;

    const int t = threadIdx.x;
    const int bd = blockIdx.x;   // [0, BG*512)
    const size_t base = (size_t)bd * 8192;
    const ushort_t* qp = qT + base;
    const ushort_t* kp = kT + base;
    const ushort_t* vp = vTT + base;

    // stage Q, K, V tiles (swizzled)
#pragma unroll
    for (int it = 0; it < 4; ++it) {
        int e = it * 2048 + t * 8;
        int n = e >> 6, pc = (e >> 3) & 7;
        int gq = pc ^ (n & 7);
        *(short8*)&Qs[n * 64 + gq * 8] = *(const short8*)(qp + e);
        *(short8*)&Ks[n * 64 + gq * 8] = *(const short8*)(kp + e);
        int p = e >> 7, mc = (e >> 3) & 15;
        int gv = mc ^ (p & 7);
        *(short8*)&Vs[p * 128 + gv * 8] = *(const short8*)(vp + e);
    }
    __syncthreads();

    const int lane = t & 63, w = t >> 6;
    const int lrow = lane & 15, lquad = lane >> 4;

    // ---- S = Q' K'^T : rows n in [w*32, w*32+32) ----
    f32x4 acc[2][8];
#pragma unroll
    for (int nt = 0; nt < 2; ++nt)
#pragma unroll
        for (int mt = 0; mt < 8; ++mt) acc[nt][mt] = (f32x4){0.f, 0.f, 0.f, 0.f};

    short8 aQ[2][2];
#pragma unroll
    for (int nt = 0; nt < 2; ++nt) {
        int n = w * 32 + nt * 16 + lrow;
#pragma unroll
        for (int s = 0; s < 2; ++s) {
            int g = (s * 4 + lquad) ^ (n & 7);
            aQ[nt][s] = *(const short8*)&Qs[n * 64 + g * 8];
        }
    }
#pragma unroll
    for (int mt = 0; mt < 8; ++mt) {
        int m = mt * 16 + lrow;
#pragma unroll
        for (int s = 0; s < 2; ++s) {
            int g = (s * 4 + lquad) ^ (m & 7);
            short8 bK = *(const short8*)&Ks[m * 64 + g * 8];
#pragma unroll
            for (int nt = 0; nt < 2; ++nt)
                acc[nt][mt] = __builtin_amdgcn_mfma_f32_16x16x32_bf16(aQ[nt][s], bK, acc[nt][mt], 0, 0, 0);
        }
    }
    __syncthreads();  // all waves done reading Qs/Ks; Ps may now overwrite them

    // ---- softmax over m ----
    float* attnp = attn + (size_t)bd * (NBLK * NBLK);
#pragma unroll
    for (int nt = 0; nt < 2; ++nt) {
        int nbase = w * 32 + nt * 16;
#pragma unroll
        for (int r = 0; r < 4; ++r) {
            int row = nbase + lquad * 4 + r;
            float pv[8];
            float mx = -1e30f;
#pragma unroll
            for (int mt = 0; mt < 8; ++mt) { pv[mt] = acc[nt][mt][r]; mx = fmaxf(mx, pv[mt]); }
#pragma unroll
            for (int msk = 1; msk < 16; msk <<= 1) mx = fmaxf(mx, __shfl_xor(mx, msk, 64));
            float sum = 0.f;
#pragma unroll
            for (int mt = 0; mt < 8; ++mt) {
                pv[mt] = exp2f((pv[mt] - mx) * 1.4426950408889634f);
                sum += pv[mt];
            }
#pragma unroll
            for (int msk = 1; msk < 16; msk <<= 1) sum += __shfl_xor(sum, msk, 64);
            float inv = 1.0f / sum;
#pragma unroll
            for (int mt = 0; mt < 8; ++mt) {
                float a = pv[mt] * inv;
                int m = mt * 16 + lrow;
                __builtin_nontemporal_store(a, attnp + (size_t)row * NBLK + m);
                int g = (m >> 3) ^ (row & 7);
                Ps[row * 128 + g * 8 + (m & 7)] = f2bf(a);
            }
        }
    }
    // no barrier: PV reads only this wave's Ps rows (wave-private);
    // same-wave ds ordering is handled by lgkmcnt.

    // ---- O = A V' : [128 n x 64 p], K over m=128 ----
    f32x4 oacc[2][4];
#pragma unroll
    for (int nt = 0; nt < 2; ++nt)
#pragma unroll
        for (int pt = 0; pt < 4; ++pt) oacc[nt][pt] = (f32x4){0.f, 0.f, 0.f, 0.f};

#pragma unroll
    for (int s = 0; s < 4; ++s) {
        short8 aP[2];
#pragma unroll
        for (int nt = 0; nt < 2; ++nt) {
            int n = w * 32 + nt * 16 + lrow;
            int g = (s * 4 + lquad) ^ (n & 7);
            aP[nt] = *(const short8*)&Ps[n * 128 + g * 8];
        }
#pragma unroll
        for (int pt = 0; pt < 4; ++pt) {
            int prow = pt * 16 + lrow;
            int gv = (s * 4 + lquad) ^ (prow & 7);
            short8 bV = *(const short8*)&Vs[prow * 128 + gv * 8];
#pragma unroll
            for (int nt = 0; nt < 2; ++nt)
                oacc[nt][pt] = __builtin_amdgcn_mfma_f32_16x16x32_bf16(aP[nt], bV, oacc[nt][pt], 0, 0, 0);
        }
    }

    ushort_t* op = outT + base;
#pragma unroll
    for (int nt = 0; nt < 2; ++nt)
#pragma unroll
        for (int pt = 0; pt < 4; ++pt)
#pragma unroll
            for (int r = 0; r < 4; ++r) {
                int row = w * 32 + nt * 16 + lquad * 4 + r;
                int p = pt * 16 + lrow;
                op[row * PER + p] = f2bf(oacc[nt][pt][r]);  // cached: read by ko (L3-resident)
            }
}

// ---- K_o: outT [BG,D,L] bf16 -> out [BG,L,D] fp32, LDS-free ----------------
__global__ __launch_bounds__(256) void ko(const ushort_t* __restrict__ outT,
                                          float* __restrict__ out) {
    const int t = threadIdx.x;
    const int l0 = blockIdx.x * 64 + 4 * (t & 15);
    const int d0 = blockIdx.y * 64 + 4 * (t >> 4);
    const int b = blockIdx.z;    // [0, BG)
    const ushort_t* sp = outT + (size_t)b * DD * LSEQ;
    float* op = out + (size_t)b * LSEQ * DD;
    uint2v ld[4];
#pragma unroll
    for (int dd = 0; dd < 4; ++dd)
        ld[dd] = *(const uint2v*)(sp + (size_t)(d0 + dd) * LSEQ + l0);
#pragma unroll
    for (int j = 0; j < 4; ++j) {
        f32x4 o;
#pragma unroll
        for (int dd = 0; dd < 4; ++dd)
            o[dd] = bf2f((ushort_t)((ld[dd][j >> 1] >> ((j & 1) * 16)) & 0xffffu));
        __builtin_nontemporal_store(o, (f32x4*)(op + (size_t)(l0 + j) * DD + d0));
    }
}

extern "C" void kernel_launch(void* const* d_in, const int* in_sizes, int n_in,
                              void* d_out, int out_size, void* d_ws, size_t ws_size,
                              hipStream_t stream) {
    const float* q = (const float*)d_in[0];
    const float* k = (const float*)d_in[1];
    const float* v = (const float*)d_in[2];
    float* outp = (float*)d_out;
    float* attnp = outp + (size_t)BB * LSEQ * DD;

    // ws for ONE group (BG batches), reused across groups -> L3-resident hot set.
    const size_t perArr = (size_t)BG * DD * LSEQ;  // elements (ushort)
    ushort_t* qT  = (ushort_t*)d_ws;
    ushort_t* kT  = qT  + perArr;
    ushort_t* vTT = kT  + perArr;
    ushort_t* oT  = vTT + perArr;

    const size_t inStride  = (size_t)BG * LSEQ * DD;          // fp32 elems per group
    const size_t attStride = (size_t)BG * DD * NBLK * NBLK;   // fp32 elems per group

    for (int g = 0; g < NG; ++g) {
        const float* qg = q + (size_t)g * inStride;
        const float* kg = k + (size_t)g * inStride;
        const float* vg = v + (size_t)g * inStride;
        dim3 g1(LSEQ / 64, DD / 64, BG * 3);
        ktr<<<g1, 256, 0, stream>>>(qg, kg, vg, qT, kT, vTT);
        katt<<<dim3(BG * DD), 256, 0, stream>>>(qT, kT, vTT,
                                                attnp + (size_t)g * attStride, oT);
        dim3 g3(LSEQ / 64, DD / 64, BG);
        ko<<<g3, 256, 0, stream>>>(oT, outp + (size_t)g * inStride);
    }
}